// Round 4
// baseline (5778.636 us; speedup 1.0000x reference)
//
#include <hip/hip_runtime.h>
#include <hip/hip_bf16.h>
#include <math.h>

typedef unsigned int u32;
typedef __hip_bfloat16 bf16_t;

// bf16 pair helpers for OUR packed intermediates (u32 = [lo=elem0, hi=elem1])
__device__ __forceinline__ float blo(u32 p){ union{u32 u; float f;} c; c.u = p << 16; return c.f; }
__device__ __forceinline__ float bhi(u32 p){ union{u32 u; float f;} c; c.u = p & 0xFFFF0000u; return c.f; }
__device__ __forceinline__ bf16_t f2b(float f){ return __float2bfloat16(f); }
__device__ __forceinline__ float sigm(float x){ return 1.0f/(1.0f + expf(-x)); }

// =====================================================================
// Kernel 1: char-level word embedder. One 256-thread block per word.
// 8320 words = 8192 sentence slots + 128 target words.
// 2-layer biLSTM H=64/dir (256 gates) + MLP 128->128(relu)->128.
// f32 weights; bf16 output we_out[8320][128].
// =====================================================================
__global__ __launch_bounds__(256) void word_kernel(
    const int* __restrict__ sentences, const int* __restrict__ words,
    const float* __restrict__ emb, const float* __restrict__ wWih,
    const float* __restrict__ wWhh, const float* __restrict__ wb,
    const float* __restrict__ fW1, const float* __restrict__ fb1,
    const float* __restrict__ fW2, const float* __restrict__ fb2,
    bf16_t* __restrict__ we_out)
{
  const int w = blockIdx.x, tid = threadIdx.x;
  __shared__ int ch[16];
  __shared__ __align__(16) float x0[16][128];
  __shared__ __align__(16) float seq[16][128];
  __shared__ __align__(16) float xw[16][256];
  __shared__ __align__(16) float gl[256];
  __shared__ __align__(16) float hl[64];
  __shared__ __align__(16) float hfin[128];

  const int* cp = (w < 8192) ? (sentences + w*16) : (words + (w - 8192)*16);
  if (tid < 16) ch[tid] = cp[tid];
  __syncthreads();
  int oracc = 0;
  #pragma unroll
  for (int i = 0; i < 16; ++i) oracc |= ch[i];
  if (w < 8192 && oracc == 0){            // empty sentence slot -> zeros
    if (tid < 128) we_out[(size_t)w*128 + tid] = f2b(0.0f);
    return;
  }

  // gather char embeddings (f32): t = tid/16, c = tid%16 -> 8 floats
  {
    const int t = tid >> 4, c = tid & 15;
    const float4* src = (const float4*)(emb + (size_t)ch[t]*128 + c*8);
    float4 a = src[0], b = src[1];
    float4* dst = (float4*)&x0[t][c*8];
    dst[0] = a; dst[1] = b;
  }
  __syncthreads();

  for (int layer = 0; layer < 2; ++layer){
    const float (*xin)[128] = (layer == 0) ? x0 : seq;
    for (int dir = 0; dir < 2; ++dir){
      const int ld = layer*2 + dir;
      const float bias = wb[ld*256 + tid];

      // ---- phase P: input projections (Wih row in regs, then released) ----
      {
        float wih[128];
        const float4* wr = (const float4*)(wWih + (size_t)(ld*256 + tid)*128);
        #pragma unroll
        for (int i = 0; i < 32; ++i){ float4 v = wr[i]; wih[4*i]=v.x; wih[4*i+1]=v.y; wih[4*i+2]=v.z; wih[4*i+3]=v.w; }
        for (int t = 0; t < 16; ++t){
          const float4* xr = (const float4*)xin[t];
          float acc = bias;
          #pragma unroll
          for (int k = 0; k < 32; ++k){
            float4 xv = xr[k];
            acc += xv.x*wih[4*k] + xv.y*wih[4*k+1] + xv.z*wih[4*k+2] + xv.w*wih[4*k+3];
          }
          xw[t][tid] = acc;   // own column only
        }
      }

      // ---- phase R: recurrence (Whh row in regs) ----
      {
        float whh[64];
        const float4* wr = (const float4*)(wWhh + (size_t)(ld*256 + tid)*64);
        #pragma unroll
        for (int i = 0; i < 16; ++i){ float4 v = wr[i]; whh[4*i]=v.x; whh[4*i+1]=v.y; whh[4*i+2]=v.z; whh[4*i+3]=v.w; }
        float c = 0.0f;
        if (tid < 64) hl[tid] = 0.0f;
        __syncthreads();
        for (int step = 0; step < 16; ++step){
          const int t = dir ? (15 - step) : step;
          float acc = xw[t][tid];
          const float4* hr = (const float4*)hl;
          #pragma unroll
          for (int k = 0; k < 16; ++k){
            float4 hv = hr[k];
            acc += hv.x*whh[4*k] + hv.y*whh[4*k+1] + hv.z*whh[4*k+2] + hv.w*whh[4*k+3];
          }
          gl[tid] = acc;
          __syncthreads();
          if (tid < 64){
            float ig = sigm(gl[tid]);
            float fg = sigm(gl[64 + tid]);
            float gg = tanhf(gl[128 + tid]);
            float og = sigm(gl[192 + tid]);
            c = fg*c + ig*gg;
            float hn = og * tanhf(c);
            hl[tid] = hn;
            if (layer == 0) seq[t][dir*64 + tid] = hn;
            else if (step == 15) hfin[dir*64 + tid] = hn;  // fwd: t=15, bwd: t=0
          }
          __syncthreads();
        }
      }
    }
  }

  // MLP: relu(hfin @ fW1^T + fb1) @ fW2^T + fb2 (rows streamed, no reg arrays)
  float a1v = 0.0f;
  if (tid < 128){
    const float4* wr = (const float4*)(fW1 + (size_t)tid*128);
    float acc = fb1[tid];
    #pragma unroll
    for (int i = 0; i < 32; ++i){
      float4 v = wr[i];
      const float* hp = &hfin[i*4];
      acc += hp[0]*v.x + hp[1]*v.y + hp[2]*v.z + hp[3]*v.w;
    }
    a1v = fmaxf(acc, 0.0f);
  }
  __syncthreads();
  if (tid < 128) gl[tid] = a1v;
  __syncthreads();
  if (tid < 128){
    const float4* wr = (const float4*)(fW2 + (size_t)tid*128);
    float acc = fb2[tid];
    #pragma unroll
    for (int i = 0; i < 32; ++i){
      float4 v = wr[i];
      const float* hp = &gl[i*4];
      acc += hp[0]*v.x + hp[1]*v.y + hp[2]*v.z + hp[3]*v.w;
    }
    we_out[(size_t)w*128 + tid] = f2b(acc);
  }
}

// =====================================================================
// Kernel 2: sentence LSTM layer 0. One 512-thread block per (sentence,dir).
// Half-split: project 32 timesteps into LDS (Wih in regs), then recur
// (Whh in regs).
// =====================================================================
__global__ __launch_bounds__(512) void sent_l0(
    const bf16_t* __restrict__ we /* [128][64][128] bf16 */,
    const float* __restrict__ sWih0, const float* __restrict__ sWhh,
    const float* __restrict__ sb,
    bf16_t* __restrict__ l0out /* [128][64][256] bf16 */)
{
  const int bs = blockIdx.x >> 1, dir = blockIdx.x & 1;
  const int g = threadIdx.x;
  __shared__ __align__(16) float x[64][128];
  __shared__ __align__(16) float xw[32][512];
  __shared__ __align__(16) float gl[512];
  __shared__ __align__(16) float hl[128];

  // stage word embeddings (bf16 pairs) -> LDS f32
  {
    const u32* src = (const u32*)(we + (size_t)bs*8192);
    for (int idx = g; idx < 4096; idx += 512){
      u32 p = src[idx];
      int f = idx*2;
      x[f >> 7][f & 127]         = blo(p);
      x[(f+1) >> 7][(f+1) & 127] = bhi(p);
    }
  }
  const float bias = sb[dir*512 + g];
  float c = 0.0f;
  if (g < 128) hl[g] = 0.0f;
  __syncthreads();

  for (int half = 0; half < 2; ++half){
    const int t0 = dir ? (1 - half)*32 : half*32;
    // phase A: projections for t in [t0, t0+32)
    {
      float wih[128];
      const float4* wr = (const float4*)(sWih0 + (size_t)(dir*512 + g)*128);
      #pragma unroll
      for (int i = 0; i < 32; ++i){ float4 v = wr[i]; wih[4*i]=v.x; wih[4*i+1]=v.y; wih[4*i+2]=v.z; wih[4*i+3]=v.w; }
      for (int sh = 0; sh < 32; ++sh){
        const float4* xr = (const float4*)x[t0 + sh];
        float acc = bias;
        #pragma unroll
        for (int k = 0; k < 32; ++k){
          float4 xv = xr[k];
          acc += xv.x*wih[4*k] + xv.y*wih[4*k+1] + xv.z*wih[4*k+2] + xv.w*wih[4*k+3];
        }
        xw[sh][g] = acc;   // own column
      }
    }
    // phase B: 32 recurrence steps
    {
      float whh[128];
      const float4* wr = (const float4*)(sWhh + (size_t)(dir*512 + g)*128);
      #pragma unroll
      for (int i = 0; i < 32; ++i){ float4 v = wr[i]; whh[4*i]=v.x; whh[4*i+1]=v.y; whh[4*i+2]=v.z; whh[4*i+3]=v.w; }
      for (int sh = 0; sh < 32; ++sh){
        const int sg = half*32 + sh;
        const int t  = dir ? (63 - sg) : sg;
        float acc = xw[t - t0][g];
        const float4* hr = (const float4*)hl;
        #pragma unroll
        for (int k = 0; k < 32; ++k){
          float4 hv = hr[k];
          acc += hv.x*whh[4*k] + hv.y*whh[4*k+1] + hv.z*whh[4*k+2] + hv.w*whh[4*k+3];
        }
        gl[g] = acc;
        __syncthreads();
        if (g < 128){
          float ig = sigm(gl[g]);
          float fg = sigm(gl[128 + g]);
          float gg = tanhf(gl[256 + g]);
          float og = sigm(gl[384 + g]);
          c = fg*c + ig*gg;
          float hn = og * tanhf(c);
          hl[g] = hn;
          l0out[((size_t)bs*64 + t)*256 + dir*128 + g] = f2b(hn);
        }
        __syncthreads();
      }
    }
  }
}

// =====================================================================
// Kernel 3: sentence LSTM layer 1 (Din=256). Projection split into two
// 128-wide k-passes so Wih never exceeds 128 regs.
// =====================================================================
__global__ __launch_bounds__(512) void sent_l1(
    const bf16_t* __restrict__ l0out /* [128][64][256] bf16 */,
    const float* __restrict__ sWih1, const float* __restrict__ sWhh,
    const float* __restrict__ sb,
    float* __restrict__ sfin /* [128][256] f32 */)
{
  const int bs = blockIdx.x >> 1, dir = blockIdx.x & 1;
  const int g = threadIdx.x;
  __shared__ __align__(16) float xs[32][256];
  __shared__ __align__(16) float xw[32][512];
  __shared__ __align__(16) float gl[512];
  __shared__ __align__(16) float hl[128];

  const float bias = sb[(2 + dir)*512 + g];
  float c = 0.0f;
  if (g < 128) hl[g] = 0.0f;
  __syncthreads();

  for (int half = 0; half < 2; ++half){
    const int t0 = dir ? (1 - half)*32 : half*32;
    // stage xs <- l0out[bs][t0..t0+32)[256] (bf16 pairs -> f32)
    {
      const u32* src = (const u32*)(l0out + ((size_t)bs*64 + t0)*256);
      for (int idx = g; idx < 4096; idx += 512){
        u32 p = src[idx];
        int f = idx*2;
        xs[f >> 8][f & 255]         = blo(p);
        xs[(f+1) >> 8][(f+1) & 255] = bhi(p);
      }
    }
    __syncthreads();
    // phase A: projections in two 128-wide k-passes
    for (int p = 0; p < 2; ++p){
      float wih[128];
      const float4* wr = (const float4*)(sWih1 + (size_t)(dir*512 + g)*256 + p*128);
      #pragma unroll
      for (int i = 0; i < 32; ++i){ float4 v = wr[i]; wih[4*i]=v.x; wih[4*i+1]=v.y; wih[4*i+2]=v.z; wih[4*i+3]=v.w; }
      for (int sh = 0; sh < 32; ++sh){
        const float4* xr = (const float4*)&xs[sh][p*128];
        float acc = (p == 0) ? bias : xw[sh][g];
        #pragma unroll
        for (int k = 0; k < 32; ++k){
          float4 xv = xr[k];
          acc += xv.x*wih[4*k] + xv.y*wih[4*k+1] + xv.z*wih[4*k+2] + xv.w*wih[4*k+3];
        }
        xw[sh][g] = acc;   // own column
      }
    }
    // phase B: 32 recurrence steps
    {
      float whh[128];
      const float4* wr = (const float4*)(sWhh + (size_t)((2 + dir)*512 + g)*128);
      #pragma unroll
      for (int i = 0; i < 32; ++i){ float4 v = wr[i]; whh[4*i]=v.x; whh[4*i+1]=v.y; whh[4*i+2]=v.z; whh[4*i+3]=v.w; }
      for (int sh = 0; sh < 32; ++sh){
        const int sg = half*32 + sh;
        const int t  = dir ? (63 - sg) : sg;
        float acc = xw[t - t0][g];
        const float4* hr = (const float4*)hl;
        #pragma unroll
        for (int k = 0; k < 32; ++k){
          float4 hv = hr[k];
          acc += hv.x*whh[4*k] + hv.y*whh[4*k+1] + hv.z*whh[4*k+2] + hv.w*whh[4*k+3];
        }
        gl[g] = acc;
        __syncthreads();
        if (g < 128){
          float ig = sigm(gl[g]);
          float fg = sigm(gl[128 + g]);
          float gg = tanhf(gl[256 + g]);
          float og = sigm(gl[384 + g]);
          c = fg*c + ig*gg;
          float hn = og * tanhf(c);
          hl[g] = hn;
          if (sg == 63) sfin[(size_t)bs*256 + dir*128 + g] = hn;
        }
        __syncthreads();
      }
    }
  }
}

// =====================================================================
// Kernel 4: sentence MLP + classifier + log-softmax. One block/sentence.
// Output: float32 [128][2].
// =====================================================================
__global__ __launch_bounds__(256) void head_kernel(
    const float* __restrict__ sfin, const bf16_t* __restrict__ wet,
    const float* __restrict__ sW1, const float* __restrict__ sb1,
    const float* __restrict__ sW2, const float* __restrict__ sb2,
    const float* __restrict__ cW0, const float* __restrict__ cb0,
    const float* __restrict__ cW1, const float* __restrict__ cb1,
    const float* __restrict__ cW2, const float* __restrict__ cb2,
    float* __restrict__ out /* [128][2] f32 */)
{
  const int bs = blockIdx.x, tid = threadIdx.x;
  __shared__ __align__(16) float hin[256];
  __shared__ __align__(16) float a1[256];
  __shared__ __align__(16) float xcat[384];
  __shared__ __align__(16) float b0o[256];
  __shared__ __align__(16) float h1o[128];
  __shared__ float lg[2];

  hin[tid] = sfin[(size_t)bs*256 + tid];
  if (tid < 64){   // unpack 128 bf16 word-embedding values
    const u32* src = (const u32*)(wet + (size_t)bs*128);
    u32 p = src[tid];
    xcat[256 + tid*2]     = blo(p);
    xcat[256 + tid*2 + 1] = bhi(p);
  }
  __syncthreads();
  {
    const float4* wr = (const float4*)(sW1 + (size_t)tid*256);
    float acc = sb1[tid];
    #pragma unroll
    for (int i = 0; i < 64; ++i){
      float4 v = wr[i]; const float* hp = &hin[i*4];
      acc += hp[0]*v.x + hp[1]*v.y + hp[2]*v.z + hp[3]*v.w;
    }
    a1[tid] = fmaxf(acc, 0.0f);
  }
  __syncthreads();
  {
    const float4* wr = (const float4*)(sW2 + (size_t)tid*256);
    float acc = sb2[tid];
    #pragma unroll
    for (int i = 0; i < 64; ++i){
      float4 v = wr[i]; const float* hp = &a1[i*4];
      acc += hp[0]*v.x + hp[1]*v.y + hp[2]*v.z + hp[3]*v.w;
    }
    xcat[tid] = acc;
  }
  __syncthreads();
  {
    const float4* wr = (const float4*)(cW0 + (size_t)tid*384);
    float acc = cb0[tid];
    #pragma unroll
    for (int i = 0; i < 96; ++i){
      float4 v = wr[i]; const float* hp = &xcat[i*4];
      acc += hp[0]*v.x + hp[1]*v.y + hp[2]*v.z + hp[3]*v.w;
    }
    b0o[tid] = fmaxf(acc, 0.0f);
  }
  __syncthreads();
  if (tid < 128){
    const float4* wr = (const float4*)(cW1 + (size_t)tid*256);
    float acc = cb1[tid];
    #pragma unroll
    for (int i = 0; i < 64; ++i){
      float4 v = wr[i]; const float* hp = &b0o[i*4];
      acc += hp[0]*v.x + hp[1]*v.y + hp[2]*v.z + hp[3]*v.w;
    }
    h1o[tid] = fmaxf(acc, 0.0f);
  }
  __syncthreads();
  if (tid < 2){
    const float4* wr = (const float4*)(cW2 + (size_t)tid*128);
    float acc = cb2[tid];
    #pragma unroll
    for (int i = 0; i < 32; ++i){
      float4 v = wr[i]; const float* hp = &h1o[i*4];
      acc += hp[0]*v.x + hp[1]*v.y + hp[2]*v.z + hp[3]*v.w;
    }
    lg[tid] = acc;
  }
  __syncthreads();
  if (tid == 0){
    float m = fmaxf(lg[0], lg[1]);
    float lse = m + logf(expf(lg[0] - m) + expf(lg[1] - m));
    out[bs*2 + 0] = lg[0] - lse;
    out[bs*2 + 1] = lg[1] - lse;
  }
}

extern "C" void kernel_launch(void* const* d_in, const int* in_sizes, int n_in,
                              void* d_out, int out_size, void* d_ws, size_t ws_size,
                              hipStream_t stream) {
  const int*   sentences = (const int*)d_in[0];
  const int*   words     = (const int*)d_in[1];
  const float* emb    = (const float*)d_in[2];
  const float* wWih   = (const float*)d_in[3];
  const float* wWhh   = (const float*)d_in[4];
  const float* wb     = (const float*)d_in[5];
  const float* fW1    = (const float*)d_in[6];
  const float* fb1    = (const float*)d_in[7];
  const float* fW2    = (const float*)d_in[8];
  const float* fb2    = (const float*)d_in[9];
  const float* sWih0  = (const float*)d_in[10];
  const float* sWih1  = (const float*)d_in[11];
  const float* sWhh   = (const float*)d_in[12];
  const float* sb     = (const float*)d_in[13];
  const float* sW1    = (const float*)d_in[14];
  const float* sb1    = (const float*)d_in[15];
  const float* sW2    = (const float*)d_in[16];
  const float* sb2    = (const float*)d_in[17];
  const float* cW0    = (const float*)d_in[18];
  const float* cb0    = (const float*)d_in[19];
  const float* cW1    = (const float*)d_in[20];
  const float* cb1    = (const float*)d_in[21];
  const float* cW2    = (const float*)d_in[22];
  const float* cb2    = (const float*)d_in[23];

  // workspace (~6.46 MB): we bf16[8320][128]; l0o bf16[128][64][256]; sfin f32[128][256]
  bf16_t* we   = (bf16_t*)d_ws;
  bf16_t* l0o  = we + (size_t)8320*128;
  float*  sfin = (float*)(l0o + (size_t)128*64*256);
  bf16_t* wet  = we + (size_t)8192*128;   // target-word embeddings

  word_kernel<<<dim3(8320), dim3(256), 0, stream>>>(
      sentences, words, emb, wWih, wWhh, wb, fW1, fb1, fW2, fb2, we);
  sent_l0<<<dim3(256), dim3(512), 0, stream>>>(we, sWih0, sWhh, sb, l0o);
  sent_l1<<<dim3(256), dim3(512), 0, stream>>>(l0o, sWih1, sWhh, sb, sfin);
  head_kernel<<<dim3(128), dim3(256), 0, stream>>>(
      sfin, wet, sW1, sb1, sW2, sb2, cW0, cb0, cW1, cb1, cW2, cb2,
      (float*)d_out);
}

// Round 5
// 2720.735 us; speedup vs baseline: 2.1239x; 2.1239x over previous
//
#include <hip/hip_runtime.h>
#include <hip/hip_bf16.h>
#include <math.h>

typedef unsigned int u32;
typedef unsigned short u16;
typedef __hip_bfloat16 bf16_t;
typedef float f32x4 __attribute__((ext_vector_type(4)));
typedef short bf16x8 __attribute__((ext_vector_type(8)));

// bf16 pair helpers for packed intermediates (u32 = [lo=elem0, hi=elem1])
__device__ __forceinline__ float blo(u32 p){ union{u32 u; float f;} c; c.u = p << 16; return c.f; }
__device__ __forceinline__ float bhi(u32 p){ union{u32 u; float f;} c; c.u = p & 0xFFFF0000u; return c.f; }
__device__ __forceinline__ bf16_t f2b(float f){ return __float2bfloat16(f); }
__device__ __forceinline__ float sigm(float x){ return 1.0f/(1.0f + expf(-x)); }
// f32 -> bf16 bits, round-to-nearest-even
__device__ __forceinline__ u16 f2bu(float f){
  union{float f; u32 u;} c; c.f = f;
  u32 u = c.u + 0x7FFFu + ((c.u >> 16) & 1u);
  return (u16)(u >> 16);
}

// =====================================================================
// Kernel 1 (MFMA): char-level word embedder, 16 words per 256-thread block.
// Batched over words: G[16w,256g] = X_t[16w,128] @ Wih^T + H[16w,64] @ Whh^T.
// mfma_f32_16x16x32_bf16; weights in VGPRs (bf16 B-frags); X/seq/H in LDS
// with XOR chunk swizzle. Wave W owns N-tiles {W,W+4,W+8,W+12} => holds
// i,f,g,o of units W*16+(lane&15) for words (lane>>4)*4+r -> lane-local c/h.
// One barrier/step (H double-buffered). MLP 128->128(relu)->128 also MFMA.
// =====================================================================
__global__ __launch_bounds__(256) void word_mfma(
    const int* __restrict__ sentences, const int* __restrict__ words,
    const float* __restrict__ emb, const float* __restrict__ wWih,
    const float* __restrict__ wWhh, const float* __restrict__ wb,
    const float* __restrict__ fW1, const float* __restrict__ fb1,
    const float* __restrict__ fW2, const float* __restrict__ fb2,
    bf16_t* __restrict__ we_out /* [8320][128] bf16 */)
{
  const int blk  = blockIdx.x;        // 520 blocks x 16 words
  const int tid  = threadIdx.x;
  const int lane = tid & 63;
  const int wv   = tid >> 6;          // wave 0..3
  const int lr   = lane & 15;         // row group (M / cols of D)
  const int lg   = lane >> 4;         // k group 0..3

  __shared__ __align__(16) u16 Xs[16*16*128];   // 64KB char embeds  [w][t][c^( w&15)][8]
  __shared__ __align__(16) u16 SQ[16*16*128];   // 64KB layer0 out   same swizzle
  __shared__ __align__(16) u16 Hb[2][16*64];    // 4KB h dbuf        [w][c^(w&7)][8]
  __shared__ __align__(16) u16 HF[16*128];      // 4KB final hiddens [w][c^(w&15)][8]
  __shared__ __align__(16) u16 A1[16*128];      // 4KB mlp hidden
  __shared__ int chs[256];
  __shared__ int emptyf[16];

  const int wbase = blk*16;
  {
    int w = tid >> 4, t = tid & 15;
    int gw = wbase + w;
    chs[tid] = (gw < 8192) ? sentences[gw*16 + t] : words[(gw - 8192)*16 + t];
  }
  __syncthreads();
  if (tid < 16){
    int acc = 0;
    #pragma unroll
    for (int i = 0; i < 16; ++i) acc |= chs[tid*16 + i];
    emptyf[tid] = (wbase + tid < 8192) && (acc == 0);
  }
  // gather char embeddings: thread = (w,t), 128 f32 -> 16 swizzled bf16x8 chunks
  {
    int w = tid >> 4, t = tid & 15;
    const float4* er = (const float4*)(emb + (size_t)chs[tid]*128);
    u16* dst = &Xs[(w*16 + t)*128];
    #pragma unroll
    for (int c2 = 0; c2 < 16; ++c2){
      float4 a = er[c2*2], b = er[c2*2 + 1];
      u16* d = dst + (c2 ^ (w & 15))*8;
      d[0]=f2bu(a.x); d[1]=f2bu(a.y); d[2]=f2bu(a.z); d[3]=f2bu(a.w);
      d[4]=f2bu(b.x); d[5]=f2bu(b.y); d[6]=f2bu(b.z); d[7]=f2bu(b.w);
    }
  }
  __syncthreads();

  for (int layer = 0; layer < 2; ++layer){
    const u16* XIN = layer ? SQ : Xs;
    for (int dir = 0; dir < 2; ++dir){
      const int ld = layer*2 + dir;
      // B-fragments: Wih (4 tiles x 4 ksteps), Whh (4 tiles x 2 ksteps)
      bf16x8 bih[4][4], bhh[4][2];
      float bias[4];
      #pragma unroll
      for (int j = 0; j < 4; ++j){
        const int col = (wv + 4*j)*16 + lr;
        bias[j] = wb[ld*256 + col];
        const float* sih = wWih + ((size_t)(ld*256 + col))*128;
        #pragma unroll
        for (int kk = 0; kk < 4; ++kk){
          const float* s = sih + kk*32 + lg*8;
          bf16x8 v;
          #pragma unroll
          for (int i = 0; i < 8; ++i) v[i] = (short)f2bu(s[i]);
          bih[j][kk] = v;
        }
        const float* shh = wWhh + ((size_t)(ld*256 + col))*64;
        #pragma unroll
        for (int kk = 0; kk < 2; ++kk){
          const float* s = shh + kk*32 + lg*8;
          bf16x8 v;
          #pragma unroll
          for (int i = 0; i < 8; ++i) v[i] = (short)f2bu(s[i]);
          bhh[j][kk] = v;
        }
      }
      float cst[4] = {0.f, 0.f, 0.f, 0.f};
      for (int i = tid; i < 16*64; i += 256) Hb[0][i] = 0;
      __syncthreads();
      int cur = 0;
      for (int step = 0; step < 16; ++step){
        const int t = dir ? (15 - step) : step;
        f32x4 ac[4];
        #pragma unroll
        for (int j = 0; j < 4; ++j) ac[j] = (f32x4){bias[j], bias[j], bias[j], bias[j]};
        // input projection: A = X_t[16,128]
        #pragma unroll
        for (int kk = 0; kk < 4; ++kk){
          const int c = (kk*4 + lg) ^ lr;
          bf16x8 a = *(const bf16x8*)&XIN[((lr*16 + t)*16 + c)*8];
          #pragma unroll
          for (int j = 0; j < 4; ++j)
            ac[j] = __builtin_amdgcn_mfma_f32_16x16x32_bf16(a, bih[j][kk], ac[j], 0, 0, 0);
        }
        // recurrence: A = H[16,64]
        #pragma unroll
        for (int kk = 0; kk < 2; ++kk){
          const int c = (kk*4 + lg) ^ (lr & 7);
          bf16x8 a = *(const bf16x8*)&Hb[cur][(lr*8 + c)*8];
          #pragma unroll
          for (int j = 0; j < 4; ++j)
            ac[j] = __builtin_amdgcn_mfma_f32_16x16x32_bf16(a, bhh[j][kk], ac[j], 0, 0, 0);
        }
        // gates: ac[0]=i ac[1]=f ac[2]=g ac[3]=o; unit u, words lg*4+r
        const int u = wv*16 + lr;
        #pragma unroll
        for (int r = 0; r < 4; ++r){
          const int w = lg*4 + r;
          float ig = sigm(ac[0][r]);
          float fg = sigm(ac[1][r]);
          float gg = tanhf(ac[2][r]);
          float og = sigm(ac[3][r]);
          cst[r] = fg*cst[r] + ig*gg;
          float hn = og * tanhf(cst[r]);
          u16 hb = f2bu(hn);
          Hb[cur^1][(w*8 + ((u >> 3) ^ (w & 7)))*8 + (u & 7)] = hb;
          const int d = dir*64 + u;
          const int dc = (d >> 3) ^ (w & 15);
          if (layer == 0)       SQ[((w*16 + t)*16 + dc)*8 + (d & 7)] = hb;
          else if (step == 15)  HF[(w*16 + dc)*8 + (d & 7)] = hb;
        }
        __syncthreads();
        cur ^= 1;
      }
    }
  }

  // MLP GEMM1: a1 = relu(HF[16,128] @ fW1^T + fb1); tiles {wv, wv+4}
  {
    bf16x8 b1[2][4]; float bs[2];
    #pragma unroll
    for (int j = 0; j < 2; ++j){
      const int col = (wv + 4*j)*16 + lr;
      bs[j] = fb1[col];
      const float* src = fW1 + (size_t)col*128;
      #pragma unroll
      for (int kk = 0; kk < 4; ++kk){
        const float* s = src + kk*32 + lg*8;
        bf16x8 v;
        #pragma unroll
        for (int i = 0; i < 8; ++i) v[i] = (short)f2bu(s[i]);
        b1[j][kk] = v;
      }
    }
    f32x4 ac[2];
    #pragma unroll
    for (int j = 0; j < 2; ++j) ac[j] = (f32x4){bs[j], bs[j], bs[j], bs[j]};
    #pragma unroll
    for (int kk = 0; kk < 4; ++kk){
      const int c = (kk*4 + lg) ^ lr;
      bf16x8 a = *(const bf16x8*)&HF[(lr*16 + c)*8];
      #pragma unroll
      for (int j = 0; j < 2; ++j)
        ac[j] = __builtin_amdgcn_mfma_f32_16x16x32_bf16(a, b1[j][kk], ac[j], 0, 0, 0);
    }
    #pragma unroll
    for (int j = 0; j < 2; ++j)
      #pragma unroll
      for (int r = 0; r < 4; ++r){
        const int w = lg*4 + r, d = (wv + 4*j)*16 + lr;
        A1[(w*16 + ((d >> 3) ^ (w & 15)))*8 + (d & 7)] = f2bu(fmaxf(ac[j][r], 0.f));
      }
  }
  __syncthreads();
  // MLP GEMM2: we = a1 @ fW2^T + fb2 (masked for empty sentence slots)
  {
    bf16x8 b2[2][4]; float bs[2];
    #pragma unroll
    for (int j = 0; j < 2; ++j){
      const int col = (wv + 4*j)*16 + lr;
      bs[j] = fb2[col];
      const float* src = fW2 + (size_t)col*128;
      #pragma unroll
      for (int kk = 0; kk < 4; ++kk){
        const float* s = src + kk*32 + lg*8;
        bf16x8 v;
        #pragma unroll
        for (int i = 0; i < 8; ++i) v[i] = (short)f2bu(s[i]);
        b2[j][kk] = v;
      }
    }
    f32x4 ac[2];
    #pragma unroll
    for (int j = 0; j < 2; ++j) ac[j] = (f32x4){bs[j], bs[j], bs[j], bs[j]};
    #pragma unroll
    for (int kk = 0; kk < 4; ++kk){
      const int c = (kk*4 + lg) ^ lr;
      bf16x8 a = *(const bf16x8*)&A1[(lr*16 + c)*8];
      #pragma unroll
      for (int j = 0; j < 2; ++j)
        ac[j] = __builtin_amdgcn_mfma_f32_16x16x32_bf16(a, b2[j][kk], ac[j], 0, 0, 0);
    }
    u16* wo = (u16*)we_out;
    #pragma unroll
    for (int j = 0; j < 2; ++j)
      #pragma unroll
      for (int r = 0; r < 4; ++r){
        const int w = lg*4 + r, col = (wv + 4*j)*16 + lr;
        wo[(size_t)(wbase + w)*128 + col] = emptyf[w] ? (u16)0 : f2bu(ac[j][r]);
      }
  }
}

// =====================================================================
// Kernel 2: sentence LSTM layer 0 (unchanged from passing round).
// =====================================================================
__global__ __launch_bounds__(512) void sent_l0(
    const bf16_t* __restrict__ we, const float* __restrict__ sWih0,
    const float* __restrict__ sWhh, const float* __restrict__ sb,
    bf16_t* __restrict__ l0out)
{
  const int bs = blockIdx.x >> 1, dir = blockIdx.x & 1;
  const int g = threadIdx.x;
  __shared__ __align__(16) float x[64][128];
  __shared__ __align__(16) float xw[32][512];
  __shared__ __align__(16) float gl[512];
  __shared__ __align__(16) float hl[128];

  {
    const u32* src = (const u32*)(we + (size_t)bs*8192);
    for (int idx = g; idx < 4096; idx += 512){
      u32 p = src[idx];
      int f = idx*2;
      x[f >> 7][f & 127]         = blo(p);
      x[(f+1) >> 7][(f+1) & 127] = bhi(p);
    }
  }
  const float bias = sb[dir*512 + g];
  float c = 0.0f;
  if (g < 128) hl[g] = 0.0f;
  __syncthreads();

  for (int half = 0; half < 2; ++half){
    const int t0 = dir ? (1 - half)*32 : half*32;
    {
      float wih[128];
      const float4* wr = (const float4*)(sWih0 + (size_t)(dir*512 + g)*128);
      #pragma unroll
      for (int i = 0; i < 32; ++i){ float4 v = wr[i]; wih[4*i]=v.x; wih[4*i+1]=v.y; wih[4*i+2]=v.z; wih[4*i+3]=v.w; }
      for (int sh = 0; sh < 32; ++sh){
        const float4* xr = (const float4*)x[t0 + sh];
        float acc = bias;
        #pragma unroll
        for (int k = 0; k < 32; ++k){
          float4 xv = xr[k];
          acc += xv.x*wih[4*k] + xv.y*wih[4*k+1] + xv.z*wih[4*k+2] + xv.w*wih[4*k+3];
        }
        xw[sh][g] = acc;
      }
    }
    {
      float whh[128];
      const float4* wr = (const float4*)(sWhh + (size_t)(dir*512 + g)*128);
      #pragma unroll
      for (int i = 0; i < 32; ++i){ float4 v = wr[i]; whh[4*i]=v.x; whh[4*i+1]=v.y; whh[4*i+2]=v.z; whh[4*i+3]=v.w; }
      for (int sh = 0; sh < 32; ++sh){
        const int sg = half*32 + sh;
        const int t  = dir ? (63 - sg) : sg;
        float acc = xw[t - t0][g];
        const float4* hr = (const float4*)hl;
        #pragma unroll
        for (int k = 0; k < 32; ++k){
          float4 hv = hr[k];
          acc += hv.x*whh[4*k] + hv.y*whh[4*k+1] + hv.z*whh[4*k+2] + hv.w*whh[4*k+3];
        }
        gl[g] = acc;
        __syncthreads();
        if (g < 128){
          float ig = sigm(gl[g]);
          float fg = sigm(gl[128 + g]);
          float gg = tanhf(gl[256 + g]);
          float og = sigm(gl[384 + g]);
          c = fg*c + ig*gg;
          float hn = og * tanhf(c);
          hl[g] = hn;
          l0out[((size_t)bs*64 + t)*256 + dir*128 + g] = f2b(hn);
        }
        __syncthreads();
      }
    }
  }
}

// =====================================================================
// Kernel 3: sentence LSTM layer 1 (unchanged from passing round).
// =====================================================================
__global__ __launch_bounds__(512) void sent_l1(
    const bf16_t* __restrict__ l0out, const float* __restrict__ sWih1,
    const float* __restrict__ sWhh, const float* __restrict__ sb,
    float* __restrict__ sfin)
{
  const int bs = blockIdx.x >> 1, dir = blockIdx.x & 1;
  const int g = threadIdx.x;
  __shared__ __align__(16) float xs[32][256];
  __shared__ __align__(16) float xw[32][512];
  __shared__ __align__(16) float gl[512];
  __shared__ __align__(16) float hl[128];

  const float bias = sb[(2 + dir)*512 + g];
  float c = 0.0f;
  if (g < 128) hl[g] = 0.0f;
  __syncthreads();

  for (int half = 0; half < 2; ++half){
    const int t0 = dir ? (1 - half)*32 : half*32;
    {
      const u32* src = (const u32*)(l0out + ((size_t)bs*64 + t0)*256);
      for (int idx = g; idx < 4096; idx += 512){
        u32 p = src[idx];
        int f = idx*2;
        xs[f >> 8][f & 255]         = blo(p);
        xs[(f+1) >> 8][(f+1) & 255] = bhi(p);
      }
    }
    __syncthreads();
    for (int p = 0; p < 2; ++p){
      float wih[128];
      const float4* wr = (const float4*)(sWih1 + (size_t)(dir*512 + g)*256 + p*128);
      #pragma unroll
      for (int i = 0; i < 32; ++i){ float4 v = wr[i]; wih[4*i]=v.x; wih[4*i+1]=v.y; wih[4*i+2]=v.z; wih[4*i+3]=v.w; }
      for (int sh = 0; sh < 32; ++sh){
        const float4* xr = (const float4*)&xs[sh][p*128];
        float acc = (p == 0) ? bias : xw[sh][g];
        #pragma unroll
        for (int k = 0; k < 32; ++k){
          float4 xv = xr[k];
          acc += xv.x*wih[4*k] + xv.y*wih[4*k+1] + xv.z*wih[4*k+2] + xv.w*wih[4*k+3];
        }
        xw[sh][g] = acc;
      }
    }
    {
      float whh[128];
      const float4* wr = (const float4*)(sWhh + (size_t)((2 + dir)*512 + g)*128);
      #pragma unroll
      for (int i = 0; i < 32; ++i){ float4 v = wr[i]; whh[4*i]=v.x; whh[4*i+1]=v.y; whh[4*i+2]=v.z; whh[4*i+3]=v.w; }
      for (int sh = 0; sh < 32; ++sh){
        const int sg = half*32 + sh;
        const int t  = dir ? (63 - sg) : sg;
        float acc = xw[t - t0][g];
        const float4* hr = (const float4*)hl;
        #pragma unroll
        for (int k = 0; k < 32; ++k){
          float4 hv = hr[k];
          acc += hv.x*whh[4*k] + hv.y*whh[4*k+1] + hv.z*whh[4*k+2] + hv.w*whh[4*k+3];
        }
        gl[g] = acc;
        __syncthreads();
        if (g < 128){
          float ig = sigm(gl[g]);
          float fg = sigm(gl[128 + g]);
          float gg = tanhf(gl[256 + g]);
          float og = sigm(gl[384 + g]);
          c = fg*c + ig*gg;
          float hn = og * tanhf(c);
          hl[g] = hn;
          if (sg == 63) sfin[(size_t)bs*256 + dir*128 + g] = hn;
        }
        __syncthreads();
      }
    }
  }
}

// =====================================================================
// Kernel 4: head (unchanged from passing round). Output f32 [128][2].
// =====================================================================
__global__ __launch_bounds__(256) void head_kernel(
    const float* __restrict__ sfin, const bf16_t* __restrict__ wet,
    const float* __restrict__ sW1, const float* __restrict__ sb1,
    const float* __restrict__ sW2, const float* __restrict__ sb2,
    const float* __restrict__ cW0, const float* __restrict__ cb0,
    const float* __restrict__ cW1, const float* __restrict__ cb1,
    const float* __restrict__ cW2, const float* __restrict__ cb2,
    float* __restrict__ out)
{
  const int bs = blockIdx.x, tid = threadIdx.x;
  __shared__ __align__(16) float hin[256];
  __shared__ __align__(16) float a1[256];
  __shared__ __align__(16) float xcat[384];
  __shared__ __align__(16) float b0o[256];
  __shared__ __align__(16) float h1o[128];
  __shared__ float lg[2];

  hin[tid] = sfin[(size_t)bs*256 + tid];
  if (tid < 64){
    const u32* src = (const u32*)(wet + (size_t)bs*128);
    u32 p = src[tid];
    xcat[256 + tid*2]     = blo(p);
    xcat[256 + tid*2 + 1] = bhi(p);
  }
  __syncthreads();
  {
    const float4* wr = (const float4*)(sW1 + (size_t)tid*256);
    float acc = sb1[tid];
    #pragma unroll
    for (int i = 0; i < 64; ++i){
      float4 v = wr[i]; const float* hp = &hin[i*4];
      acc += hp[0]*v.x + hp[1]*v.y + hp[2]*v.z + hp[3]*v.w;
    }
    a1[tid] = fmaxf(acc, 0.0f);
  }
  __syncthreads();
  {
    const float4* wr = (const float4*)(sW2 + (size_t)tid*256);
    float acc = sb2[tid];
    #pragma unroll
    for (int i = 0; i < 64; ++i){
      float4 v = wr[i]; const float* hp = &a1[i*4];
      acc += hp[0]*v.x + hp[1]*v.y + hp[2]*v.z + hp[3]*v.w;
    }
    xcat[tid] = acc;
  }
  __syncthreads();
  {
    const float4* wr = (const float4*)(cW0 + (size_t)tid*384);
    float acc = cb0[tid];
    #pragma unroll
    for (int i = 0; i < 96; ++i){
      float4 v = wr[i]; const float* hp = &xcat[i*4];
      acc += hp[0]*v.x + hp[1]*v.y + hp[2]*v.z + hp[3]*v.w;
    }
    b0o[tid] = fmaxf(acc, 0.0f);
  }
  __syncthreads();
  if (tid < 128){
    const float4* wr = (const float4*)(cW1 + (size_t)tid*256);
    float acc = cb1[tid];
    #pragma unroll
    for (int i = 0; i < 64; ++i){
      float4 v = wr[i]; const float* hp = &b0o[i*4];
      acc += hp[0]*v.x + hp[1]*v.y + hp[2]*v.z + hp[3]*v.w;
    }
    h1o[tid] = fmaxf(acc, 0.0f);
  }
  __syncthreads();
  if (tid < 2){
    const float4* wr = (const float4*)(cW2 + (size_t)tid*128);
    float acc = cb2[tid];
    #pragma unroll
    for (int i = 0; i < 32; ++i){
      float4 v = wr[i]; const float* hp = &h1o[i*4];
      acc += hp[0]*v.x + hp[1]*v.y + hp[2]*v.z + hp[3]*v.w;
    }
    lg[tid] = acc;
  }
  __syncthreads();
  if (tid == 0){
    float m = fmaxf(lg[0], lg[1]);
    float lse = m + logf(expf(lg[0] - m) + expf(lg[1] - m));
    out[bs*2 + 0] = lg[0] - lse;
    out[bs*2 + 1] = lg[1] - lse;
  }
}

extern "C" void kernel_launch(void* const* d_in, const int* in_sizes, int n_in,
                              void* d_out, int out_size, void* d_ws, size_t ws_size,
                              hipStream_t stream) {
  const int*   sentences = (const int*)d_in[0];
  const int*   words     = (const int*)d_in[1];
  const float* emb    = (const float*)d_in[2];
  const float* wWih   = (const float*)d_in[3];
  const float* wWhh   = (const float*)d_in[4];
  const float* wb     = (const float*)d_in[5];
  const float* fW1    = (const float*)d_in[6];
  const float* fb1    = (const float*)d_in[7];
  const float* fW2    = (const float*)d_in[8];
  const float* fb2    = (const float*)d_in[9];
  const float* sWih0  = (const float*)d_in[10];
  const float* sWih1  = (const float*)d_in[11];
  const float* sWhh   = (const float*)d_in[12];
  const float* sb     = (const float*)d_in[13];
  const float* sW1    = (const float*)d_in[14];
  const float* sb1    = (const float*)d_in[15];
  const float* sW2    = (const float*)d_in[16];
  const float* sb2    = (const float*)d_in[17];
  const float* cW0    = (const float*)d_in[18];
  const float* cb0    = (const float*)d_in[19];
  const float* cW1    = (const float*)d_in[20];
  const float* cb1    = (const float*)d_in[21];
  const float* cW2    = (const float*)d_in[22];
  const float* cb2    = (const float*)d_in[23];

  // workspace (~6.46 MB): we bf16[8320][128]; l0o bf16[128][64][256]; sfin f32[128][256]
  bf16_t* we   = (bf16_t*)d_ws;
  bf16_t* l0o  = we + (size_t)8320*128;
  float*  sfin = (float*)(l0o + (size_t)128*64*256);
  bf16_t* wet  = we + (size_t)8192*128;

  word_mfma<<<dim3(520), dim3(256), 0, stream>>>(
      sentences, words, emb, wWih, wWhh, wb, fW1, fb1, fW2, fb2, we);
  sent_l0<<<dim3(256), dim3(512), 0, stream>>>(we, sWih0, sWhh, sb, l0o);
  sent_l1<<<dim3(256), dim3(512), 0, stream>>>(l0o, sWih1, sWhh, sb, sfin);
  head_kernel<<<dim3(128), dim3(256), 0, stream>>>(
      sfin, wet, sW1, sb1, sW2, sb2, cW0, cb0, cW1, cb1, cW2, cb2,
      (float*)d_out);
}

// Round 6
// 878.356 us; speedup vs baseline: 6.5789x; 3.0975x over previous
//
#include <hip/hip_runtime.h>
#include <hip/hip_bf16.h>
#include <math.h>

typedef unsigned int u32;
typedef unsigned short u16;
typedef __hip_bfloat16 bf16_t;
typedef float f32x4 __attribute__((ext_vector_type(4)));
typedef short bf16x8 __attribute__((ext_vector_type(8)));

// bf16 pair helpers for packed intermediates (u32 = [lo=elem0, hi=elem1])
__device__ __forceinline__ float blo(u32 p){ union{u32 u; float f;} c; c.u = p << 16; return c.f; }
__device__ __forceinline__ float bhi(u32 p){ union{u32 u; float f;} c; c.u = p & 0xFFFF0000u; return c.f; }
__device__ __forceinline__ bf16_t f2b(float f){ return __float2bfloat16(f); }
__device__ __forceinline__ float sigm(float x){ return 1.0f/(1.0f + expf(-x)); }
// f32 -> bf16 bits, round-to-nearest-even
__device__ __forceinline__ u16 f2bu(float f){
  union{float f; u32 u;} c; c.f = f;
  u32 u = c.u + 0x7FFFu + ((c.u >> 16) & 1u);
  return (u16)(u >> 16);
}
__device__ __forceinline__ bf16x8 pack8(const float* s){
  bf16x8 v;
  #pragma unroll
  for (int i = 0; i < 8; ++i) v[i] = (short)f2bu(s[i]);
  return v;
}

// =====================================================================
// Kernel 1 (MFMA): char-level word embedder, 16 words per 256-thread block.
// (unchanged from passing round 5)
// =====================================================================
__global__ __launch_bounds__(256) void word_mfma(
    const int* __restrict__ sentences, const int* __restrict__ words,
    const float* __restrict__ emb, const float* __restrict__ wWih,
    const float* __restrict__ wWhh, const float* __restrict__ wb,
    const float* __restrict__ fW1, const float* __restrict__ fb1,
    const float* __restrict__ fW2, const float* __restrict__ fb2,
    bf16_t* __restrict__ we_out /* [8320][128] bf16 */)
{
  const int blk  = blockIdx.x;        // 520 blocks x 16 words
  const int tid  = threadIdx.x;
  const int lane = tid & 63;
  const int wv   = tid >> 6;          // wave 0..3
  const int lr   = lane & 15;         // row group (M / cols of D)
  const int lg   = lane >> 4;         // k group 0..3

  __shared__ __align__(16) u16 Xs[16*16*128];   // 64KB char embeds  [w][t][c^(w&15)][8]
  __shared__ __align__(16) u16 SQ[16*16*128];   // 64KB layer0 out   same swizzle
  __shared__ __align__(16) u16 Hb[2][16*64];    // 4KB h dbuf        [w][c^(w&7)][8]
  __shared__ __align__(16) u16 HF[16*128];      // 4KB final hiddens [w][c^(w&15)][8]
  __shared__ __align__(16) u16 A1[16*128];      // 4KB mlp hidden
  __shared__ int chs[256];
  __shared__ int emptyf[16];

  const int wbase = blk*16;
  {
    int w = tid >> 4, t = tid & 15;
    int gw = wbase + w;
    chs[tid] = (gw < 8192) ? sentences[gw*16 + t] : words[(gw - 8192)*16 + t];
  }
  __syncthreads();
  if (tid < 16){
    int acc = 0;
    #pragma unroll
    for (int i = 0; i < 16; ++i) acc |= chs[tid*16 + i];
    emptyf[tid] = (wbase + tid < 8192) && (acc == 0);
  }
  // gather char embeddings: thread = (w,t), 128 f32 -> 16 swizzled bf16x8 chunks
  {
    int w = tid >> 4, t = tid & 15;
    const float4* er = (const float4*)(emb + (size_t)chs[tid]*128);
    u16* dst = &Xs[(w*16 + t)*128];
    #pragma unroll
    for (int c2 = 0; c2 < 16; ++c2){
      float4 a = er[c2*2], b = er[c2*2 + 1];
      u16* d = dst + (c2 ^ (w & 15))*8;
      d[0]=f2bu(a.x); d[1]=f2bu(a.y); d[2]=f2bu(a.z); d[3]=f2bu(a.w);
      d[4]=f2bu(b.x); d[5]=f2bu(b.y); d[6]=f2bu(b.z); d[7]=f2bu(b.w);
    }
  }
  __syncthreads();

  for (int layer = 0; layer < 2; ++layer){
    const u16* XIN = layer ? SQ : Xs;
    for (int dir = 0; dir < 2; ++dir){
      const int ld = layer*2 + dir;
      bf16x8 bih[4][4], bhh[4][2];
      float bias[4];
      #pragma unroll
      for (int j = 0; j < 4; ++j){
        const int col = (wv + 4*j)*16 + lr;
        bias[j] = wb[ld*256 + col];
        const float* sih = wWih + ((size_t)(ld*256 + col))*128;
        #pragma unroll
        for (int kk = 0; kk < 4; ++kk) bih[j][kk] = pack8(sih + kk*32 + lg*8);
        const float* shh = wWhh + ((size_t)(ld*256 + col))*64;
        #pragma unroll
        for (int kk = 0; kk < 2; ++kk) bhh[j][kk] = pack8(shh + kk*32 + lg*8);
      }
      float cst[4] = {0.f, 0.f, 0.f, 0.f};
      for (int i = tid; i < 16*64; i += 256) Hb[0][i] = 0;
      __syncthreads();
      int cur = 0;
      for (int step = 0; step < 16; ++step){
        const int t = dir ? (15 - step) : step;
        f32x4 ac[4];
        #pragma unroll
        for (int j = 0; j < 4; ++j) ac[j] = (f32x4){bias[j], bias[j], bias[j], bias[j]};
        #pragma unroll
        for (int kk = 0; kk < 4; ++kk){
          const int c = (kk*4 + lg) ^ lr;
          bf16x8 a = *(const bf16x8*)&XIN[((lr*16 + t)*16 + c)*8];
          #pragma unroll
          for (int j = 0; j < 4; ++j)
            ac[j] = __builtin_amdgcn_mfma_f32_16x16x32_bf16(a, bih[j][kk], ac[j], 0, 0, 0);
        }
        #pragma unroll
        for (int kk = 0; kk < 2; ++kk){
          const int c = (kk*4 + lg) ^ (lr & 7);
          bf16x8 a = *(const bf16x8*)&Hb[cur][(lr*8 + c)*8];
          #pragma unroll
          for (int j = 0; j < 4; ++j)
            ac[j] = __builtin_amdgcn_mfma_f32_16x16x32_bf16(a, bhh[j][kk], ac[j], 0, 0, 0);
        }
        const int u = wv*16 + lr;
        #pragma unroll
        for (int r = 0; r < 4; ++r){
          const int w = lg*4 + r;
          float ig = sigm(ac[0][r]);
          float fg = sigm(ac[1][r]);
          float gg = tanhf(ac[2][r]);
          float og = sigm(ac[3][r]);
          cst[r] = fg*cst[r] + ig*gg;
          float hn = og * tanhf(cst[r]);
          u16 hb = f2bu(hn);
          Hb[cur^1][(w*8 + ((u >> 3) ^ (w & 7)))*8 + (u & 7)] = hb;
          const int d = dir*64 + u;
          const int dc = (d >> 3) ^ (w & 15);
          if (layer == 0)       SQ[((w*16 + t)*16 + dc)*8 + (d & 7)] = hb;
          else if (step == 15)  HF[(w*16 + dc)*8 + (d & 7)] = hb;
        }
        __syncthreads();
        cur ^= 1;
      }
    }
  }

  // MLP GEMM1
  {
    bf16x8 b1[2][4]; float bs[2];
    #pragma unroll
    for (int j = 0; j < 2; ++j){
      const int col = (wv + 4*j)*16 + lr;
      bs[j] = fb1[col];
      const float* src = fW1 + (size_t)col*128;
      #pragma unroll
      for (int kk = 0; kk < 4; ++kk) b1[j][kk] = pack8(src + kk*32 + lg*8);
    }
    f32x4 ac[2];
    #pragma unroll
    for (int j = 0; j < 2; ++j) ac[j] = (f32x4){bs[j], bs[j], bs[j], bs[j]};
    #pragma unroll
    for (int kk = 0; kk < 4; ++kk){
      const int c = (kk*4 + lg) ^ lr;
      bf16x8 a = *(const bf16x8*)&HF[(lr*16 + c)*8];
      #pragma unroll
      for (int j = 0; j < 2; ++j)
        ac[j] = __builtin_amdgcn_mfma_f32_16x16x32_bf16(a, b1[j][kk], ac[j], 0, 0, 0);
    }
    #pragma unroll
    for (int j = 0; j < 2; ++j)
      #pragma unroll
      for (int r = 0; r < 4; ++r){
        const int w = lg*4 + r, d = (wv + 4*j)*16 + lr;
        A1[(w*16 + ((d >> 3) ^ (w & 15)))*8 + (d & 7)] = f2bu(fmaxf(ac[j][r], 0.f));
      }
  }
  __syncthreads();
  // MLP GEMM2 (masked for empty sentence slots)
  {
    bf16x8 b2[2][4]; float bs[2];
    #pragma unroll
    for (int j = 0; j < 2; ++j){
      const int col = (wv + 4*j)*16 + lr;
      bs[j] = fb2[col];
      const float* src = fW2 + (size_t)col*128;
      #pragma unroll
      for (int kk = 0; kk < 4; ++kk) b2[j][kk] = pack8(src + kk*32 + lg*8);
    }
    f32x4 ac[2];
    #pragma unroll
    for (int j = 0; j < 2; ++j) ac[j] = (f32x4){bs[j], bs[j], bs[j], bs[j]};
    #pragma unroll
    for (int kk = 0; kk < 4; ++kk){
      const int c = (kk*4 + lg) ^ lr;
      bf16x8 a = *(const bf16x8*)&A1[(lr*16 + c)*8];
      #pragma unroll
      for (int j = 0; j < 2; ++j)
        ac[j] = __builtin_amdgcn_mfma_f32_16x16x32_bf16(a, b2[j][kk], ac[j], 0, 0, 0);
    }
    u16* wo = (u16*)we_out;
    #pragma unroll
    for (int j = 0; j < 2; ++j)
      #pragma unroll
      for (int r = 0; r < 4; ++r){
        const int w = lg*4 + r, col = (wv + 4*j)*16 + lr;
        wo[(size_t)(wbase + w)*128 + col] = emptyf[w] ? (u16)0 : f2bu(ac[j][r]);
      }
  }
}

// =====================================================================
// Kernel 2 (MFMA): sentence LSTM layer 0. 16 sentences x 1 dir per block;
// 16 blocks x 512 threads (8 waves). Wave w owns gate-tiles {w,w+8,w+16,w+24}
// => i,f,g,o of unit w*16+lr lane-local. H dbuf in LDS (XOR chunk swizzle);
// X A-frags direct from global `we` (bf16), prefetched 1 step ahead.
// =====================================================================
__global__ __launch_bounds__(512, 2) void sent_l0_mfma(
    const bf16_t* __restrict__ we /* [8192][128] bf16 */,
    const float* __restrict__ sWih0, const float* __restrict__ sWhh,
    const float* __restrict__ sb,
    bf16_t* __restrict__ l0out /* [128][64][256] bf16 */)
{
  const int dir = blockIdx.x & 1;
  const int sg0 = (blockIdx.x >> 1) << 4;     // sentence base
  const int tid = threadIdx.x;
  const int lane = tid & 63, wv = tid >> 6;   // wave 0..7
  const int lr = lane & 15, lg = lane >> 4;

  __shared__ __align__(16) u16 Hs[2][2048];   // [sent][chunk^(sent)][8], 128 units

  bf16x8 bih[4][4], bhh[4][4];
  float bias[4];
  #pragma unroll
  for (int j = 0; j < 4; ++j){
    const int g = (wv + 8*j)*16 + lr;
    bias[j] = sb[dir*512 + g];
    const float* pih = sWih0 + (size_t)(dir*512 + g)*128 + lg*8;
    const float* phh = sWhh  + (size_t)(dir*512 + g)*128 + lg*8;   // layer 0
    #pragma unroll
    for (int kk = 0; kk < 4; ++kk){
      bih[j][kk] = pack8(pih + kk*32);
      bhh[j][kk] = pack8(phh + kk*32);
    }
  }
  for (int i = tid; i < 2048; i += 512) Hs[0][i] = 0;
  float cst[4] = {0.f, 0.f, 0.f, 0.f};
  __syncthreads();

  const u16* xbase = (const u16*)we + (size_t)(sg0 + lr)*64*128 + lg*8;
  u16* lob = (u16*)l0out;
  int cur = 0;
  bf16x8 xfn[4];
  {
    const int t0 = dir ? 63 : 0;
    const u16* xr = xbase + (size_t)t0*128;
    #pragma unroll
    for (int kk = 0; kk < 4; ++kk) xfn[kk] = *(const bf16x8*)(xr + kk*32);
  }
  for (int step = 0; step < 64; ++step){
    const int t = dir ? (63 - step) : step;
    bf16x8 xf[4];
    #pragma unroll
    for (int kk = 0; kk < 4; ++kk) xf[kk] = xfn[kk];
    if (step < 63){
      const int tn = dir ? (62 - step) : (step + 1);
      const u16* xr = xbase + (size_t)tn*128;
      #pragma unroll
      for (int kk = 0; kk < 4; ++kk) xfn[kk] = *(const bf16x8*)(xr + kk*32);
    }
    f32x4 ac[4];
    #pragma unroll
    for (int j = 0; j < 4; ++j) ac[j] = (f32x4){bias[j], bias[j], bias[j], bias[j]};
    // hh: A = H[16,128] from LDS
    #pragma unroll
    for (int kk = 0; kk < 4; ++kk){
      const bf16x8 ha = *(const bf16x8*)&Hs[cur][(lr*16 + ((kk*4 + lg) ^ lr))*8];
      #pragma unroll
      for (int j = 0; j < 4; ++j)
        ac[j] = __builtin_amdgcn_mfma_f32_16x16x32_bf16(ha, bhh[j][kk], ac[j], 0, 0, 0);
    }
    // ih: A = X_t[16,128]
    #pragma unroll
    for (int kk = 0; kk < 4; ++kk){
      #pragma unroll
      for (int j = 0; j < 4; ++j)
        ac[j] = __builtin_amdgcn_mfma_f32_16x16x32_bf16(xf[kk], bih[j][kk], ac[j], 0, 0, 0);
    }
    const int u = wv*16 + lr;
    #pragma unroll
    for (int r = 0; r < 4; ++r){
      const int s = lg*4 + r;
      float ig = sigm(ac[0][r]);
      float fg = sigm(ac[1][r]);
      float gg = tanhf(ac[2][r]);
      float og = sigm(ac[3][r]);
      cst[r] = fg*cst[r] + ig*gg;
      float hn = og * tanhf(cst[r]);
      u16 hb = f2bu(hn);
      Hs[cur^1][(s*16 + ((u >> 3) ^ s))*8 + (u & 7)] = hb;
      lob[((size_t)(sg0 + s)*64 + t)*256 + dir*128 + u] = hb;
    }
    __syncthreads();
    cur ^= 1;
  }
}

// =====================================================================
// Kernel 3 (MFMA): sentence LSTM layer 1 (Din=256). Same structure;
// X A-frags (8 k-steps) direct from l0out, loaded in two groups of 4.
// Writes only final hiddens sfin[sent][256] (f32).
// =====================================================================
__global__ __launch_bounds__(512, 2) void sent_l1_mfma(
    const bf16_t* __restrict__ l0out /* [128][64][256] bf16 */,
    const float* __restrict__ sWih1, const float* __restrict__ sWhh,
    const float* __restrict__ sb,
    float* __restrict__ sfin /* [128][256] f32 */)
{
  const int dir = blockIdx.x & 1;
  const int sg0 = (blockIdx.x >> 1) << 4;
  const int tid = threadIdx.x;
  const int lane = tid & 63, wv = tid >> 6;
  const int lr = lane & 15, lg = lane >> 4;

  __shared__ __align__(16) u16 Hs[2][2048];

  bf16x8 bih[4][8], bhh[4][4];
  float bias[4];
  #pragma unroll
  for (int j = 0; j < 4; ++j){
    const int g = (wv + 8*j)*16 + lr;
    bias[j] = sb[(2 + dir)*512 + g];
    const float* pih = sWih1 + (size_t)(dir*512 + g)*256 + lg*8;
    const float* phh = sWhh  + (size_t)((2 + dir)*512 + g)*128 + lg*8;  // layer 1
    #pragma unroll
    for (int kk = 0; kk < 8; ++kk) bih[j][kk] = pack8(pih + kk*32);
    #pragma unroll
    for (int kk = 0; kk < 4; ++kk) bhh[j][kk] = pack8(phh + kk*32);
  }
  for (int i = tid; i < 2048; i += 512) Hs[0][i] = 0;
  float cst[4] = {0.f, 0.f, 0.f, 0.f};
  __syncthreads();

  const u16* xbase = (const u16*)l0out + (size_t)(sg0 + lr)*64*256 + lg*8;
  int cur = 0;
  for (int step = 0; step < 64; ++step){
    const int t = dir ? (63 - step) : step;
    const u16* xr = xbase + (size_t)t*256;
    f32x4 ac[4];
    #pragma unroll
    for (int j = 0; j < 4; ++j) ac[j] = (f32x4){bias[j], bias[j], bias[j], bias[j]};
    // issue first X group, then hh from LDS (hides some latency)
    bf16x8 xf[4];
    #pragma unroll
    for (int kk = 0; kk < 4; ++kk) xf[kk] = *(const bf16x8*)(xr + kk*32);
    #pragma unroll
    for (int kk = 0; kk < 4; ++kk){
      const bf16x8 ha = *(const bf16x8*)&Hs[cur][(lr*16 + ((kk*4 + lg) ^ lr))*8];
      #pragma unroll
      for (int j = 0; j < 4; ++j)
        ac[j] = __builtin_amdgcn_mfma_f32_16x16x32_bf16(ha, bhh[j][kk], ac[j], 0, 0, 0);
    }
    #pragma unroll
    for (int kk = 0; kk < 4; ++kk){
      #pragma unroll
      for (int j = 0; j < 4; ++j)
        ac[j] = __builtin_amdgcn_mfma_f32_16x16x32_bf16(xf[kk], bih[j][kk], ac[j], 0, 0, 0);
    }
    #pragma unroll
    for (int kk = 0; kk < 4; ++kk) xf[kk] = *(const bf16x8*)(xr + 128 + kk*32);
    #pragma unroll
    for (int kk = 0; kk < 4; ++kk){
      #pragma unroll
      for (int j = 0; j < 4; ++j)
        ac[j] = __builtin_amdgcn_mfma_f32_16x16x32_bf16(xf[kk], bih[j][4 + kk], ac[j], 0, 0, 0);
    }
    const int u = wv*16 + lr;
    #pragma unroll
    for (int r = 0; r < 4; ++r){
      const int s = lg*4 + r;
      float ig = sigm(ac[0][r]);
      float fg = sigm(ac[1][r]);
      float gg = tanhf(ac[2][r]);
      float og = sigm(ac[3][r]);
      cst[r] = fg*cst[r] + ig*gg;
      float hn = og * tanhf(cst[r]);
      Hs[cur^1][(s*16 + ((u >> 3) ^ s))*8 + (u & 7)] = f2bu(hn);
      if (step == 63) sfin[(size_t)(sg0 + s)*256 + dir*128 + u] = hn;
    }
    __syncthreads();
    cur ^= 1;
  }
}

// =====================================================================
// Kernel 4: head (unchanged). Output f32 [128][2].
// =====================================================================
__global__ __launch_bounds__(256) void head_kernel(
    const float* __restrict__ sfin, const bf16_t* __restrict__ wet,
    const float* __restrict__ sW1, const float* __restrict__ sb1,
    const float* __restrict__ sW2, const float* __restrict__ sb2,
    const float* __restrict__ cW0, const float* __restrict__ cb0,
    const float* __restrict__ cW1, const float* __restrict__ cb1,
    const float* __restrict__ cW2, const float* __restrict__ cb2,
    float* __restrict__ out)
{
  const int bs = blockIdx.x, tid = threadIdx.x;
  __shared__ __align__(16) float hin[256];
  __shared__ __align__(16) float a1[256];
  __shared__ __align__(16) float xcat[384];
  __shared__ __align__(16) float b0o[256];
  __shared__ __align__(16) float h1o[128];
  __shared__ float lg[2];

  hin[tid] = sfin[(size_t)bs*256 + tid];
  if (tid < 64){
    const u32* src = (const u32*)(wet + (size_t)bs*128);
    u32 p = src[tid];
    xcat[256 + tid*2]     = blo(p);
    xcat[256 + tid*2 + 1] = bhi(p);
  }
  __syncthreads();
  {
    const float4* wr = (const float4*)(sW1 + (size_t)tid*256);
    float acc = sb1[tid];
    #pragma unroll
    for (int i = 0; i < 64; ++i){
      float4 v = wr[i]; const float* hp = &hin[i*4];
      acc += hp[0]*v.x + hp[1]*v.y + hp[2]*v.z + hp[3]*v.w;
    }
    a1[tid] = fmaxf(acc, 0.0f);
  }
  __syncthreads();
  {
    const float4* wr = (const float4*)(sW2 + (size_t)tid*256);
    float acc = sb2[tid];
    #pragma unroll
    for (int i = 0; i < 64; ++i){
      float4 v = wr[i]; const float* hp = &a1[i*4];
      acc += hp[0]*v.x + hp[1]*v.y + hp[2]*v.z + hp[3]*v.w;
    }
    xcat[tid] = acc;
  }
  __syncthreads();
  {
    const float4* wr = (const float4*)(cW0 + (size_t)tid*384);
    float acc = cb0[tid];
    #pragma unroll
    for (int i = 0; i < 96; ++i){
      float4 v = wr[i]; const float* hp = &xcat[i*4];
      acc += hp[0]*v.x + hp[1]*v.y + hp[2]*v.z + hp[3]*v.w;
    }
    b0o[tid] = fmaxf(acc, 0.0f);
  }
  __syncthreads();
  if (tid < 128){
    const float4* wr = (const float4*)(cW1 + (size_t)tid*256);
    float acc = cb1[tid];
    #pragma unroll
    for (int i = 0; i < 64; ++i){
      float4 v = wr[i]; const float* hp = &b0o[i*4];
      acc += hp[0]*v.x + hp[1]*v.y + hp[2]*v.z + hp[3]*v.w;
    }
    h1o[tid] = fmaxf(acc, 0.0f);
  }
  __syncthreads();
  if (tid < 2){
    const float4* wr = (const float4*)(cW2 + (size_t)tid*128);
    float acc = cb2[tid];
    #pragma unroll
    for (int i = 0; i < 32; ++i){
      float4 v = wr[i]; const float* hp = &h1o[i*4];
      acc += hp[0]*v.x + hp[1]*v.y + hp[2]*v.z + hp[3]*v.w;
    }
    lg[tid] = acc;
  }
  __syncthreads();
  if (tid == 0){
    float m = fmaxf(lg[0], lg[1]);
    float lse = m + logf(expf(lg[0] - m) + expf(lg[1] - m));
    out[bs*2 + 0] = lg[0] - lse;
    out[bs*2 + 1] = lg[1] - lse;
  }
}

extern "C" void kernel_launch(void* const* d_in, const int* in_sizes, int n_in,
                              void* d_out, int out_size, void* d_ws, size_t ws_size,
                              hipStream_t stream) {
  const int*   sentences = (const int*)d_in[0];
  const int*   words     = (const int*)d_in[1];
  const float* emb    = (const float*)d_in[2];
  const float* wWih   = (const float*)d_in[3];
  const float* wWhh   = (const float*)d_in[4];
  const float* wb     = (const float*)d_in[5];
  const float* fW1    = (const float*)d_in[6];
  const float* fb1    = (const float*)d_in[7];
  const float* fW2    = (const float*)d_in[8];
  const float* fb2    = (const float*)d_in[9];
  const float* sWih0  = (const float*)d_in[10];
  const float* sWih1  = (const float*)d_in[11];
  const float* sWhh   = (const float*)d_in[12];
  const float* sb     = (const float*)d_in[13];
  const float* sW1    = (const float*)d_in[14];
  const float* sb1    = (const float*)d_in[15];
  const float* sW2    = (const float*)d_in[16];
  const float* sb2    = (const float*)d_in[17];
  const float* cW0    = (const float*)d_in[18];
  const float* cb0    = (const float*)d_in[19];
  const float* cW1    = (const float*)d_in[20];
  const float* cb1    = (const float*)d_in[21];
  const float* cW2    = (const float*)d_in[22];
  const float* cb2    = (const float*)d_in[23];

  // workspace (~6.46 MB): we bf16[8320][128]; l0o bf16[128][64][256]; sfin f32[128][256]
  bf16_t* we   = (bf16_t*)d_ws;
  bf16_t* l0o  = we + (size_t)8320*128;
  float*  sfin = (float*)(l0o + (size_t)128*64*256);
  bf16_t* wet  = we + (size_t)8192*128;

  word_mfma<<<dim3(520), dim3(256), 0, stream>>>(
      sentences, words, emb, wWih, wWhh, wb, fW1, fb1, fW2, fb2, we);
  sent_l0_mfma<<<dim3(16), dim3(512), 0, stream>>>(we, sWih0, sWhh, sb, l0o);
  sent_l1_mfma<<<dim3(16), dim3(512), 0, stream>>>(l0o, sWih1, sWhh, sb, sfin);
  head_kernel<<<dim3(128), dim3(256), 0, stream>>>(
      sfin, wet, sW1, sb1, sW2, sb2, cW0, cb0, cW1, cb1, cW2, cb2,
      (float*)d_out);
}

// Round 7
// 599.384 us; speedup vs baseline: 9.6410x; 1.4654x over previous
//
#include <hip/hip_runtime.h>
#include <hip/hip_bf16.h>
#include <math.h>

typedef unsigned int u32;
typedef unsigned short u16;
typedef __hip_bfloat16 bf16_t;
typedef float f32x4 __attribute__((ext_vector_type(4)));
typedef short bf16x8 __attribute__((ext_vector_type(8)));

__device__ __forceinline__ float blo(u32 p){ union{u32 u; float f;} c; c.u = p << 16; return c.f; }
__device__ __forceinline__ float bhi(u32 p){ union{u32 u; float f;} c; c.u = p & 0xFFFF0000u; return c.f; }
__device__ __forceinline__ float sigm(float x){ return 1.0f/(1.0f + expf(-x)); }
// f32 -> bf16 bits, round-to-nearest-even
__device__ __forceinline__ u16 f2bu(float f){
  union{float f; u32 u;} c; c.f = f;
  u32 u = c.u + 0x7FFFu + ((c.u >> 16) & 1u);
  return (u16)(u >> 16);
}

// ws byte offsets
#define WE_OFF   0u
#define L0O_OFF  2129920u
#define SFIN_OFF 6324224u
#define XW_OFF   6455296u
#define WB_OFF   40009728u
// bf16 weight segment element offsets inside wB
#define SEG_WWIH  0
#define SEG_WWHH  131072
#define SEG_FW1   196608
#define SEG_FW2   212992
#define SEG_SWIH0 229376
#define SEG_SWIH1 360448
#define SEG_SWHH  622592
#define SEG_TOTAL 884736

// =====================================================================
// Kernel 0: one-time f32 -> bf16 weight conversion into ws.
// =====================================================================
__global__ __launch_bounds__(256) void prep_weights(
    const float* __restrict__ wWih, const float* __restrict__ wWhh,
    const float* __restrict__ fW1,  const float* __restrict__ fW2,
    const float* __restrict__ sWih0,const float* __restrict__ sWih1,
    const float* __restrict__ sWhh, u16* __restrict__ dst)
{
  for (int i = blockIdx.x*256 + threadIdx.x; i < SEG_TOTAL; i += gridDim.x*256){
    const float* s; int off;
    if      (i < SEG_WWHH ){ s = wWih;  off = i; }
    else if (i < SEG_FW1  ){ s = wWhh;  off = i - SEG_WWHH; }
    else if (i < SEG_FW2  ){ s = fW1;   off = i - SEG_FW1; }
    else if (i < SEG_SWIH0){ s = fW2;   off = i - SEG_FW2; }
    else if (i < SEG_SWIH1){ s = sWih0; off = i - SEG_SWIH0; }
    else if (i < SEG_SWHH ){ s = sWih1; off = i - SEG_SWIH1; }
    else                   { s = sWhh;  off = i - SEG_SWHH; }
    dst[i] = f2bu(s[off]);
  }
}

// =====================================================================
// Kernel 1 (MFMA): char-level word embedder. 16 words per block,
// 512 threads (8 waves): waves 0-3 = dir0 gate tiles, waves 4-7 = dir1.
// Both directions of each layer run concurrently -> 2 passes not 4.
// Weights read as prepped bf16.
// =====================================================================
__global__ __launch_bounds__(512, 1) void word_mfma(
    const int* __restrict__ sentences, const int* __restrict__ words,
    const float* __restrict__ emb,
    const u16* __restrict__ wWihB, const u16* __restrict__ wWhhB,
    const float* __restrict__ wb,
    const u16* __restrict__ fW1B, const float* __restrict__ fb1,
    const u16* __restrict__ fW2B, const float* __restrict__ fb2,
    bf16_t* __restrict__ we_out /* [8320][128] bf16 */)
{
  const int blk  = blockIdx.x;        // 520 blocks x 16 words
  const int tid  = threadIdx.x;
  const int lane = tid & 63;
  const int wv   = tid >> 6;          // wave 0..7
  const int dq   = wv >> 2;           // direction handled by this wave
  const int wq   = wv & 3;            // gate-tile quarter within dir
  const int lr   = lane & 15;
  const int lg   = lane >> 4;

  __shared__ __align__(16) u16 Xs[16*16*128];    // 64KB char embeds [w][t][c^(w&15)][8]
  __shared__ __align__(16) u16 SQ[16*16*128];    // 64KB layer0 out  same swizzle
  __shared__ __align__(16) u16 Hb[2][2][16*64];  // 8KB  h dbuf per dir
  __shared__ __align__(16) u16 HF[16*128];       // 4KB  final hiddens
  __shared__ __align__(16) u16 A1[16*128];       // 4KB  mlp hidden
  __shared__ int chs[256];
  __shared__ int emptyf[16];

  const int wbase = blk*16;
  if (tid < 256){
    int w = tid >> 4, t = tid & 15;
    int gw = wbase + w;
    chs[tid] = (gw < 8192) ? sentences[gw*16 + t] : words[(gw - 8192)*16 + t];
  }
  __syncthreads();
  if (tid < 16){
    int acc = 0;
    #pragma unroll
    for (int i = 0; i < 16; ++i) acc |= chs[tid*16 + i];
    emptyf[tid] = (wbase + tid < 8192) && (acc == 0);
  }
  // gather char embeddings: thread = (w,t,half); 8 chunks each
  {
    int w = tid >> 5, t = (tid >> 1) & 15, hf = tid & 1;
    const float4* er = (const float4*)(emb + (size_t)chs[w*16 + t]*128);
    u16* dst = &Xs[(w*16 + t)*128];
    #pragma unroll
    for (int c2 = 0; c2 < 8; ++c2){
      const int cc = hf*8 + c2;
      float4 a = er[cc*2], b = er[cc*2 + 1];
      u16* d = dst + (cc ^ (w & 15))*8;
      d[0]=f2bu(a.x); d[1]=f2bu(a.y); d[2]=f2bu(a.z); d[3]=f2bu(a.w);
      d[4]=f2bu(b.x); d[5]=f2bu(b.y); d[6]=f2bu(b.z); d[7]=f2bu(b.w);
    }
  }
  __syncthreads();

  for (int layer = 0; layer < 2; ++layer){
    const u16* XIN = layer ? SQ : Xs;
    const int ld = layer*2 + dq;
    bf16x8 bih[4][4], bhh[4][2];
    float bias[4];
    #pragma unroll
    for (int j = 0; j < 4; ++j){
      const int col = (wq + 4*j)*16 + lr;
      bias[j] = wb[ld*256 + col];
      const u16* pih = wWihB + (size_t)(ld*256 + col)*128 + lg*8;
      #pragma unroll
      for (int kk = 0; kk < 4; ++kk) bih[j][kk] = *(const bf16x8*)(pih + kk*32);
      const u16* phh = wWhhB + (size_t)(ld*256 + col)*64 + lg*8;
      #pragma unroll
      for (int kk = 0; kk < 2; ++kk) bhh[j][kk] = *(const bf16x8*)(phh + kk*32);
    }
    float cst[4] = {0.f, 0.f, 0.f, 0.f};
    for (int i = tid; i < 2*2*16*64; i += 512) ((u16*)Hb)[i] = 0;
    __syncthreads();
    int cur = 0;
    for (int step = 0; step < 16; ++step){
      const int t = dq ? (15 - step) : step;
      f32x4 ac[4];
      #pragma unroll
      for (int j = 0; j < 4; ++j) ac[j] = (f32x4){bias[j], bias[j], bias[j], bias[j]};
      // ih: A = X_t[16,128]
      #pragma unroll
      for (int kk = 0; kk < 4; ++kk){
        const int c = (kk*4 + lg) ^ lr;
        bf16x8 a = *(const bf16x8*)&XIN[((lr*16 + t)*16 + c)*8];
        #pragma unroll
        for (int j = 0; j < 4; ++j)
          ac[j] = __builtin_amdgcn_mfma_f32_16x16x32_bf16(a, bih[j][kk], ac[j], 0, 0, 0);
      }
      // hh: A = H[16,64]
      #pragma unroll
      for (int kk = 0; kk < 2; ++kk){
        const int c = (kk*4 + lg) ^ (lr & 7);
        bf16x8 a = *(const bf16x8*)&Hb[dq][cur][(lr*8 + c)*8];
        #pragma unroll
        for (int j = 0; j < 4; ++j)
          ac[j] = __builtin_amdgcn_mfma_f32_16x16x32_bf16(a, bhh[j][kk], ac[j], 0, 0, 0);
      }
      const int u = wq*16 + lr;            // unit 0..63 within dir
      #pragma unroll
      for (int r = 0; r < 4; ++r){
        const int w = lg*4 + r;
        float ig = sigm(ac[0][r]);
        float fg = sigm(ac[1][r]);
        float gg = tanhf(ac[2][r]);
        float og = sigm(ac[3][r]);
        cst[r] = fg*cst[r] + ig*gg;
        float hn = og * tanhf(cst[r]);
        u16 hb = f2bu(hn);
        Hb[dq][cur^1][(w*8 + ((u >> 3) ^ (w & 7)))*8 + (u & 7)] = hb;
        const int d = dq*64 + u;
        const int dc = (d >> 3) ^ (w & 15);
        if (layer == 0)       SQ[((w*16 + t)*16 + dc)*8 + (d & 7)] = hb;
        else if (step == 15)  HF[(w*16 + dc)*8 + (d & 7)] = hb;
      }
      __syncthreads();
      cur ^= 1;
    }
  }

  // MLP GEMM1: 8 waves x 1 tile (128 cols)
  {
    const int col = wv*16 + lr;
    float bs = fb1[col];
    bf16x8 b1[4];
    const u16* src = fW1B + (size_t)col*128 + lg*8;
    #pragma unroll
    for (int kk = 0; kk < 4; ++kk) b1[kk] = *(const bf16x8*)(src + kk*32);
    f32x4 ac = (f32x4){bs, bs, bs, bs};
    #pragma unroll
    for (int kk = 0; kk < 4; ++kk){
      const int c = (kk*4 + lg) ^ lr;
      bf16x8 a = *(const bf16x8*)&HF[(lr*16 + c)*8];
      ac = __builtin_amdgcn_mfma_f32_16x16x32_bf16(a, b1[kk], ac, 0, 0, 0);
    }
    #pragma unroll
    for (int r = 0; r < 4; ++r){
      const int w = lg*4 + r;
      A1[(w*16 + ((col >> 3) ^ (w & 15)))*8 + (col & 7)] = f2bu(fmaxf(ac[r], 0.f));
    }
  }
  __syncthreads();
  // MLP GEMM2 (masked for empty sentence slots)
  {
    const int col = wv*16 + lr;
    float bs = fb2[col];
    bf16x8 b2[4];
    const u16* src = fW2B + (size_t)col*128 + lg*8;
    #pragma unroll
    for (int kk = 0; kk < 4; ++kk) b2[kk] = *(const bf16x8*)(src + kk*32);
    f32x4 ac = (f32x4){bs, bs, bs, bs};
    #pragma unroll
    for (int kk = 0; kk < 4; ++kk){
      const int c = (kk*4 + lg) ^ lr;
      bf16x8 a = *(const bf16x8*)&A1[(lr*16 + c)*8];
      ac = __builtin_amdgcn_mfma_f32_16x16x32_bf16(a, b2[kk], ac, 0, 0, 0);
    }
    u16* wo = (u16*)we_out;
    #pragma unroll
    for (int r = 0; r < 4; ++r){
      const int w = lg*4 + r;
      wo[(size_t)(wbase + w)*128 + col] = emptyf[w] ? (u16)0 : f2bu(ac[r]);
    }
  }
}

// =====================================================================
// Kernel 2 (MFMA GEMM): xw[row][1024] = X[row][K] @ W[1024][K]^T + b.
// Row = sentence*64 + t. Grid (512 rowblks, 4 colblks), 256 thr (4 waves),
// wave owns 4 col-tiles. Fully parallel -> all CUs.
// =====================================================================
template<int KK>
__global__ __launch_bounds__(256, 1) void xw_gemm(
    const u16* __restrict__ X, const u16* __restrict__ W,
    const float* __restrict__ bias, float* __restrict__ out)
{
  const int rowb = blockIdx.x;
  const int colb = blockIdx.y;
  const int tid = threadIdx.x;
  const int lane = tid & 63, wv = tid >> 6;
  const int lr = lane & 15, lg = lane >> 4;
  const int K = KK*32;

  bf16x8 bf[4][KK];
  f32x4 ac[4];
  #pragma unroll
  for (int j = 0; j < 4; ++j){
    const int g = colb*256 + (wv*4 + j)*16 + lr;
    const float bs = bias[g];
    ac[j] = (f32x4){bs, bs, bs, bs};
    const u16* src = W + (size_t)g*K + lg*8;
    #pragma unroll
    for (int kk = 0; kk < KK; ++kk) bf[j][kk] = *(const bf16x8*)(src + kk*32);
  }
  const u16* xr = X + (size_t)(rowb*16 + lr)*K + lg*8;
  #pragma unroll
  for (int kk = 0; kk < KK; ++kk){
    bf16x8 a = *(const bf16x8*)(xr + kk*32);
    #pragma unroll
    for (int j = 0; j < 4; ++j)
      ac[j] = __builtin_amdgcn_mfma_f32_16x16x32_bf16(a, bf[j][kk], ac[j], 0, 0, 0);
  }
  #pragma unroll
  for (int j = 0; j < 4; ++j){
    const int g = colb*256 + (wv*4 + j)*16 + lr;
    #pragma unroll
    for (int r = 0; r < 4; ++r)
      out[(size_t)(rowb*16 + lg*4 + r)*1024 + g] = ac[j][r];
  }
}

// =====================================================================
// Kernel 3 (MFMA): sentence recurrence (hh only; ih precomputed in xw).
// 16 blocks (8 sent-groups x 2 dirs), 512 thr. Wave w owns gate tiles
// {w,w+8,w+16,w+24} -> i,f,g,o of unit w*16+lr lane-local.
// =====================================================================
__global__ __launch_bounds__(512, 1) void sent_rec(
    const float* __restrict__ xw /* [8192][1024] */,
    const u16* __restrict__ sWhhB /* [4*512][128] */,
    bf16_t* __restrict__ l0out /* layer0: [8192][256] */,
    float* __restrict__ sfin /* layer1: [128][256] */,
    const int layer)
{
  const int dir = blockIdx.x & 1;
  const int sg0 = (blockIdx.x >> 1) << 4;
  const int tid = threadIdx.x;
  const int lane = tid & 63, wv = tid >> 6;
  const int lr = lane & 15, lg = lane >> 4;

  __shared__ __align__(16) u16 Hs[2][2048];

  bf16x8 bhh[4][4];
  #pragma unroll
  for (int j = 0; j < 4; ++j){
    const int g = (wv + 8*j)*16 + lr;
    const u16* p = sWhhB + (size_t)((layer*2 + dir)*512 + g)*128 + lg*8;
    #pragma unroll
    for (int kk = 0; kk < 4; ++kk) bhh[j][kk] = *(const bf16x8*)(p + kk*32);
  }
  for (int i = tid; i < 4096; i += 512) ((u16*)Hs)[i] = 0;
  float cst[4] = {0.f, 0.f, 0.f, 0.f};

  // per-thread xw gather offsets: row = (sg0 + lg*4 + r)*64 + t, col = dir*512 + (wv+8j)*16+lr
  size_t rowoff[4];
  #pragma unroll
  for (int r = 0; r < 4; ++r)
    rowoff[r] = (size_t)(sg0 + lg*4 + r)*64*1024 + dir*512 + wv*16 + lr;

  float xwv[16], xwn[16];
  {
    const int t0 = dir ? 63 : 0;
    #pragma unroll
    for (int j = 0; j < 4; ++j)
      #pragma unroll
      for (int r = 0; r < 4; ++r)
        xwv[j*4 + r] = xw[rowoff[r] + (size_t)t0*1024 + j*128];
  }
  __syncthreads();

  u16* lob = (u16*)l0out;
  int cur = 0;
  for (int step = 0; step < 64; ++step){
    const int t = dir ? (63 - step) : step;
    f32x4 ac[4];
    #pragma unroll
    for (int j = 0; j < 4; ++j)
      ac[j] = (f32x4){xwv[j*4+0], xwv[j*4+1], xwv[j*4+2], xwv[j*4+3]};
    if (step < 63){
      const int tn = dir ? (62 - step) : (step + 1);
      #pragma unroll
      for (int j = 0; j < 4; ++j)
        #pragma unroll
        for (int r = 0; r < 4; ++r)
          xwn[j*4 + r] = xw[rowoff[r] + (size_t)tn*1024 + j*128];
    }
    // hh: A = H[16 sentences, 128 units]
    #pragma unroll
    for (int kk = 0; kk < 4; ++kk){
      const bf16x8 ha = *(const bf16x8*)&Hs[cur][(lr*16 + ((kk*4 + lg) ^ lr))*8];
      #pragma unroll
      for (int j = 0; j < 4; ++j)
        ac[j] = __builtin_amdgcn_mfma_f32_16x16x32_bf16(ha, bhh[j][kk], ac[j], 0, 0, 0);
    }
    const int u = wv*16 + lr;
    #pragma unroll
    for (int r = 0; r < 4; ++r){
      const int s = lg*4 + r;
      float ig = sigm(ac[0][r]);
      float fg = sigm(ac[1][r]);
      float gg = tanhf(ac[2][r]);
      float og = sigm(ac[3][r]);
      cst[r] = fg*cst[r] + ig*gg;
      float hn = og * tanhf(cst[r]);
      Hs[cur^1][(s*16 + ((u >> 3) ^ s))*8 + (u & 7)] = f2bu(hn);
      if (layer == 0)
        lob[((size_t)(sg0 + s)*64 + t)*256 + dir*128 + u] = f2bu(hn);
      else if (step == 63)
        sfin[(size_t)(sg0 + s)*256 + dir*128 + u] = hn;
    }
    __syncthreads();
    cur ^= 1;
    #pragma unroll
    for (int i = 0; i < 16; ++i) xwv[i] = xwn[i];
  }
}

// =====================================================================
// Kernel 4: head (unchanged). Output f32 [128][2].
// =====================================================================
__global__ __launch_bounds__(256) void head_kernel(
    const float* __restrict__ sfin, const bf16_t* __restrict__ wet,
    const float* __restrict__ sW1, const float* __restrict__ sb1,
    const float* __restrict__ sW2, const float* __restrict__ sb2,
    const float* __restrict__ cW0, const float* __restrict__ cb0,
    const float* __restrict__ cW1, const float* __restrict__ cb1,
    const float* __restrict__ cW2, const float* __restrict__ cb2,
    float* __restrict__ out)
{
  const int bs = blockIdx.x, tid = threadIdx.x;
  __shared__ __align__(16) float hin[256];
  __shared__ __align__(16) float a1[256];
  __shared__ __align__(16) float xcat[384];
  __shared__ __align__(16) float b0o[256];
  __shared__ __align__(16) float h1o[128];
  __shared__ float lg[2];

  hin[tid] = sfin[(size_t)bs*256 + tid];
  if (tid < 64){
    const u32* src = (const u32*)(wet + (size_t)bs*128);
    u32 p = src[tid];
    xcat[256 + tid*2]     = blo(p);
    xcat[256 + tid*2 + 1] = bhi(p);
  }
  __syncthreads();
  {
    const float4* wr = (const float4*)(sW1 + (size_t)tid*256);
    float acc = sb1[tid];
    #pragma unroll
    for (int i = 0; i < 64; ++i){
      float4 v = wr[i]; const float* hp = &hin[i*4];
      acc += hp[0]*v.x + hp[1]*v.y + hp[2]*v.z + hp[3]*v.w;
    }
    a1[tid] = fmaxf(acc, 0.0f);
  }
  __syncthreads();
  {
    const float4* wr = (const float4*)(sW2 + (size_t)tid*256);
    float acc = sb2[tid];
    #pragma unroll
    for (int i = 0; i < 64; ++i){
      float4 v = wr[i]; const float* hp = &a1[i*4];
      acc += hp[0]*v.x + hp[1]*v.y + hp[2]*v.z + hp[3]*v.w;
    }
    xcat[tid] = acc;
  }
  __syncthreads();
  {
    const float4* wr = (const float4*)(cW0 + (size_t)tid*384);
    float acc = cb0[tid];
    #pragma unroll
    for (int i = 0; i < 96; ++i){
      float4 v = wr[i]; const float* hp = &xcat[i*4];
      acc += hp[0]*v.x + hp[1]*v.y + hp[2]*v.z + hp[3]*v.w;
    }
    b0o[tid] = fmaxf(acc, 0.0f);
  }
  __syncthreads();
  if (tid < 128){
    const float4* wr = (const float4*)(cW1 + (size_t)tid*256);
    float acc = cb1[tid];
    #pragma unroll
    for (int i = 0; i < 64; ++i){
      float4 v = wr[i]; const float* hp = &b0o[i*4];
      acc += hp[0]*v.x + hp[1]*v.y + hp[2]*v.z + hp[3]*v.w;
    }
    h1o[tid] = fmaxf(acc, 0.0f);
  }
  __syncthreads();
  if (tid < 2){
    const float4* wr = (const float4*)(cW2 + (size_t)tid*128);
    float acc = cb2[tid];
    #pragma unroll
    for (int i = 0; i < 32; ++i){
      float4 v = wr[i]; const float* hp = &h1o[i*4];
      acc += hp[0]*v.x + hp[1]*v.y + hp[2]*v.z + hp[3]*v.w;
    }
    lg[tid] = acc;
  }
  __syncthreads();
  if (tid == 0){
    float m = fmaxf(lg[0], lg[1]);
    float lse = m + logf(expf(lg[0] - m) + expf(lg[1] - m));
    out[bs*2 + 0] = lg[0] - lse;
    out[bs*2 + 1] = lg[1] - lse;
  }
}

extern "C" void kernel_launch(void* const* d_in, const int* in_sizes, int n_in,
                              void* d_out, int out_size, void* d_ws, size_t ws_size,
                              hipStream_t stream) {
  const int*   sentences = (const int*)d_in[0];
  const int*   words     = (const int*)d_in[1];
  const float* emb    = (const float*)d_in[2];
  const float* wWih   = (const float*)d_in[3];
  const float* wWhh   = (const float*)d_in[4];
  const float* wb     = (const float*)d_in[5];
  const float* fW1    = (const float*)d_in[6];
  const float* fb1    = (const float*)d_in[7];
  const float* fW2    = (const float*)d_in[8];
  const float* fb2    = (const float*)d_in[9];
  const float* sWih0  = (const float*)d_in[10];
  const float* sWih1  = (const float*)d_in[11];
  const float* sWhh   = (const float*)d_in[12];
  const float* sb     = (const float*)d_in[13];
  const float* sW1    = (const float*)d_in[14];
  const float* sb1    = (const float*)d_in[15];
  const float* sW2    = (const float*)d_in[16];
  const float* sb2    = (const float*)d_in[17];
  const float* cW0    = (const float*)d_in[18];
  const float* cb0    = (const float*)d_in[19];
  const float* cW1    = (const float*)d_in[20];
  const float* cb1    = (const float*)d_in[21];
  const float* cW2    = (const float*)d_in[22];
  const float* cb2    = (const float*)d_in[23];

  char* W = (char*)d_ws;
  bf16_t* we   = (bf16_t*)(W + WE_OFF);     // [8320][128] bf16
  bf16_t* l0o  = (bf16_t*)(W + L0O_OFF);    // [8192][256] bf16
  float*  sfin = (float*) (W + SFIN_OFF);   // [128][256] f32
  float*  xw   = (float*) (W + XW_OFF);     // [8192][1024] f32 (reused l0/l1)
  u16*    wB   = (u16*)   (W + WB_OFF);     // bf16 weights
  bf16_t* wet  = we + (size_t)8192*128;

  prep_weights<<<dim3(432), dim3(256), 0, stream>>>(
      wWih, wWhh, fW1, fW2, sWih0, sWih1, sWhh, wB);
  word_mfma<<<dim3(520), dim3(512), 0, stream>>>(
      sentences, words, emb,
      wB + SEG_WWIH, wB + SEG_WWHH, wb,
      wB + SEG_FW1, fb1, wB + SEG_FW2, fb2, we);
  xw_gemm<4><<<dim3(512, 4), dim3(256), 0, stream>>>(
      (const u16*)we, wB + SEG_SWIH0, sb, xw);
  sent_rec<<<dim3(16), dim3(512), 0, stream>>>(xw, wB + SEG_SWHH, l0o, sfin, 0);
  xw_gemm<8><<<dim3(512, 4), dim3(256), 0, stream>>>(
      (const u16*)l0o, wB + SEG_SWIH1, sb + 1024, xw);
  sent_rec<<<dim3(16), dim3(512), 0, stream>>>(xw, wB + SEG_SWHH, l0o, sfin, 1);
  head_kernel<<<dim3(128), dim3(256), 0, stream>>>(
      sfin, wet, sW1, sb1, sW2, sb2, cW0, cb0, cW1, cb1, cW2, cb2,
      (float*)d_out);
}